// Round 1
// baseline (2851.740 us; speedup 1.0000x reference)
//
#include <hip/hip_runtime.h>
#include <math.h>

#define NPTS 262144
#define D 128
#define KC 1024

// ---------------- ws layout (all 4-byte elems) ----------------
// [0, NPTS)            int   y_hat
// [NPTS, 2*NPTS)       int   order (cluster-sorted point ids)
// [2*NPTS, +KC)        int   counts
// [.., +KC)            int   cursor (exclusive-scan offsets, then bumped by scatter)
// [.., +KC)            float CC (||c||^2)

// ---------------- centroid norms ----------------
__global__ void cc_kernel(const float* __restrict__ C, float* __restrict__ CC) {
    int k = blockIdx.x * 256 + threadIdx.x;
    if (k >= KC) return;
    const float4* Cr = (const float4*)(C + (size_t)k * D);
    float s0 = 0.f, s1 = 0.f, s2 = 0.f, s3 = 0.f;
#pragma unroll
    for (int i = 0; i < D / 4; i++) {
        float4 c = Cr[i];
        s0 = fmaf(c.x, c.x, s0);
        s1 = fmaf(c.y, c.y, s1);
        s2 = fmaf(c.z, c.z, s2);
        s3 = fmaf(c.w, c.w, s3);
    }
    CC[k] = (s0 + s1) + (s2 + s3);
}

// ---------------- assignment: argmin_k ||x-c_k|| ----------------
// One thread per point; X row held in 32 float4 regs; centroid loads are
// wave-uniform (no threadIdx in address) -> compiler scalarizes to s_load.
__global__ __launch_bounds__(256, 2) void assign_kernel(
    const float* __restrict__ X,
    const float* __restrict__ C,
    const float* __restrict__ CC,
    int* __restrict__ y_hat,
    float* __restrict__ inertia)
{
    const int p = blockIdx.x * 256 + threadIdx.x;

    float4 xv[D / 4];
    const float4* Xr = (const float4*)(X + (size_t)p * D);
#pragma unroll
    for (int i = 0; i < D / 4; i++) xv[i] = Xr[i];

    float xx = 0.f;
#pragma unroll
    for (int i = 0; i < D / 4; i++) {
        xx = fmaf(xv[i].x, xv[i].x, xx);
        xx = fmaf(xv[i].y, xv[i].y, xx);
        xx = fmaf(xv[i].z, xv[i].z, xx);
        xx = fmaf(xv[i].w, xv[i].w, xx);
    }

    float best = 3.4e38f;
    int bestk = 0;
    for (int k = 0; k < KC; k++) {
        const float4* Cr = (const float4*)(C + (size_t)k * D);
        // 4 independent accumulator chains for ILP
        float d0 = 0.f, d1 = 0.f, d2a = 0.f, d3 = 0.f;
#pragma unroll
        for (int i = 0; i < D / 4; i++) {
            float4 c = Cr[i];
            d0 = fmaf(xv[i].x, c.x, d0);
            d1 = fmaf(xv[i].y, c.y, d1);
            d2a = fmaf(xv[i].z, c.z, d2a);
            d3 = fmaf(xv[i].w, c.w, d3);
        }
        float dot = (d0 + d1) + (d2a + d3);
        float d2 = CC[k] - 2.f * dot;   // argmin-equivalent (xx added later)
        if (d2 < best) { best = d2; bestk = k; }   // strict < keeps first index
    }

    y_hat[p] = bestk;
    float dist = sqrtf(fmaxf(xx + best, 0.f));

    // block-reduce dist -> one atomic per block
    __shared__ float red[256];
    red[threadIdx.x] = dist;
    __syncthreads();
    for (int s = 128; s > 0; s >>= 1) {
        if (threadIdx.x < s) red[threadIdx.x] += red[threadIdx.x + s];
        __syncthreads();
    }
    if (threadIdx.x == 0) atomicAdd(inertia, red[0]);
}

// ---------------- histogram ----------------
__global__ void hist_kernel(const int* __restrict__ y_hat, int* __restrict__ counts) {
    __shared__ int h[KC];
    for (int i = threadIdx.x; i < KC; i += 256) h[i] = 0;
    __syncthreads();
    for (int i = blockIdx.x * 256 + threadIdx.x; i < NPTS; i += gridDim.x * 256)
        atomicAdd(&h[y_hat[i]], 1);
    __syncthreads();
    for (int i = threadIdx.x; i < KC; i += 256) {
        int v = h[i];
        if (v) atomicAdd(&counts[i], v);
    }
}

// ---------------- exclusive scan (single block, 1024 threads) ----------------
__global__ void scan_kernel(const int* __restrict__ counts, int* __restrict__ cursor) {
    __shared__ int tmp[KC];
    int t = threadIdx.x;
    tmp[t] = counts[t];
    __syncthreads();
    for (int off = 1; off < KC; off <<= 1) {
        int v = tmp[t];
        int add = (t >= off) ? tmp[t - off] : 0;
        __syncthreads();
        tmp[t] = v + add;
        __syncthreads();
    }
    cursor[t] = (t == 0) ? 0 : tmp[t - 1];
}

// ---------------- scatter point ids into cluster-sorted order ----------------
__global__ void scatter_kernel(const int* __restrict__ y_hat,
                               int* __restrict__ cursor,
                               int* __restrict__ order) {
    int i = blockIdx.x * 256 + threadIdx.x;
    if (i < NPTS) {
        int pos = atomicAdd(&cursor[y_hat[i]], 1);
        order[pos] = i;
    }
}

// ---------------- segmented reduction over sorted order ----------------
#define PPB 256
__global__ __launch_bounds__(128) void segsum_kernel(
    const float* __restrict__ X, const float* __restrict__ W,
    const int* __restrict__ order, const int* __restrict__ y_hat,
    float* __restrict__ w_sum, float* __restrict__ xw_sum)
{
    const int d = threadIdx.x;          // 128 threads = one dim each
    const int i0 = blockIdx.x * PPB;
    float wacc = 0.f, xwacc = 0.f;
    int cur = -1;
    for (int i = i0; i < i0 + PPB; i++) {
        int p = order[i];               // uniform -> scalar load
        int k = y_hat[p];               // uniform
        if (k != cur) {
            if (cur >= 0) {
                atomicAdd(&w_sum[(size_t)cur * D + d], wacc);
                atomicAdd(&xw_sum[(size_t)cur * D + d], xwacc);
            }
            cur = k; wacc = 0.f; xwacc = 0.f;
        }
        float w = W[(size_t)p * D + d];
        float x = X[(size_t)p * D + d];
        wacc += w;
        xwacc = fmaf(x, w, xwacc);
    }
    if (cur >= 0) {
        atomicAdd(&w_sum[(size_t)cur * D + d], wacc);
        atomicAdd(&xw_sum[(size_t)cur * D + d], xwacc);
    }
}

extern "C" void kernel_launch(void* const* d_in, const int* in_sizes, int n_in,
                              void* d_out, int out_size, void* d_ws, size_t ws_size,
                              hipStream_t stream) {
    const float* X = (const float*)d_in[0];
    const float* W = (const float*)d_in[1];
    const float* C = (const float*)d_in[2];

    float* out      = (float*)d_out;
    float* inertia  = out;            // [1]
    float* w_sum    = out + 1;        // [KC*D]
    float* xw_sum   = out + 1 + KC * D;

    int*   y_hat  = (int*)d_ws;
    int*   order  = y_hat + NPTS;
    int*   counts = order + NPTS;
    int*   cursor = counts + KC;
    float* CC     = (float*)(cursor + KC);

    // zero outputs (harness poisons with 0xAA) and histogram bins
    hipMemsetAsync(d_out, 0, (size_t)out_size * sizeof(float), stream);
    hipMemsetAsync(counts, 0, KC * sizeof(int), stream);

    cc_kernel<<<(KC + 255) / 256, 256, 0, stream>>>(C, CC);
    assign_kernel<<<NPTS / 256, 256, 0, stream>>>(X, C, CC, y_hat, inertia);
    hist_kernel<<<256, 256, 0, stream>>>(y_hat, counts);
    scan_kernel<<<1, KC, 0, stream>>>(counts, cursor);
    scatter_kernel<<<NPTS / 256, 256, 0, stream>>>(y_hat, cursor, order);
    segsum_kernel<<<NPTS / PPB, 128, 0, stream>>>(X, W, order, y_hat, w_sum, xw_sum);
}

// Round 2
// 1411.463 us; speedup vs baseline: 2.0204x; 2.0204x over previous
//
#include <hip/hip_runtime.h>
#include <math.h>

#define NPTS 262144
#define D 128
#define KC 1024

#define BPTS 128   // points per block
#define BCENT 128  // centroids per k-tile
#define DCH 16     // d-chunk for B staging

// ---------------- centroid norms ----------------
__global__ void cc_kernel(const float* __restrict__ C, float* __restrict__ CC) {
    int k = blockIdx.x * 256 + threadIdx.x;
    if (k >= KC) return;
    const float4* Cr = (const float4*)(C + (size_t)k * D);
    float s0 = 0.f, s1 = 0.f, s2 = 0.f, s3 = 0.f;
#pragma unroll
    for (int i = 0; i < D / 4; i++) {
        float4 c = Cr[i];
        s0 = fmaf(c.x, c.x, s0);
        s1 = fmaf(c.y, c.y, s1);
        s2 = fmaf(c.z, c.z, s2);
        s3 = fmaf(c.w, c.w, s3);
    }
    CC[k] = (s0 + s1) + (s2 + s3);
}

// ---------------- assignment: GEMM-tiled argmin ----------------
// Block: 256 threads = 16 tx (centroid groups) x 16 ty (point groups).
// Thread tile: 8 points x 8 centroids (two float4 groups each).
// At[d][p] (transposed X tile, 64KB) staged once; Bt[d][c] staged per
// (ktile, dchunk). All hot LDS reads are broadcast / 2-way -> conflict-free.
__global__ __launch_bounds__(256, 2) void assign_kernel(
    const float* __restrict__ X,
    const float* __restrict__ C,
    const float* __restrict__ CC,
    int* __restrict__ y_hat,
    float* __restrict__ inertia)
{
    __shared__ float At[D][BPTS];     // 64 KB
    __shared__ float Bt[DCH][BCENT];  // 8 KB
    __shared__ float xxs[BPTS];       // 512 B

    const int t  = threadIdx.x;
    const int tx = t & 15;
    const int ty = t >> 4;
    const int pbase = blockIdx.x * BPTS;

    // ---- stage A transposed: At[d][p] = X[pbase+p][d] ----
    {
        const int dq = t & 3;   // quad group within 16-dim stripe pattern
        const int p0 = t >> 2;  // 0..63
#pragma unroll
        for (int ip = 0; ip < 2; ip++) {
            int p = p0 + 64 * ip;
            const float4* Xr = (const float4*)(X + (size_t)(pbase + p) * D);
#pragma unroll
            for (int j = 0; j < 8; j++) {
                int q = dq + 4 * j;   // quad index 0..31
                float4 v = Xr[q];
                At[q * 4 + 0][p] = v.x;
                At[q * 4 + 1][p] = v.y;
                At[q * 4 + 2][p] = v.z;
                At[q * 4 + 3][p] = v.w;
            }
        }
    }
    __syncthreads();

    // ---- per-point ||x||^2 (needed only for inertia at the end) ----
    if (t < BPTS) {
        float s = 0.f;
        for (int d = 0; d < D; d++) { float v = At[d][t]; s = fmaf(v, v, s); }
        xxs[t] = s;
    }

    float rb[8];
    int   rk[8];
#pragma unroll
    for (int i = 0; i < 8; i++) { rb[i] = 3.4e38f; rk[i] = 0; }

    for (int kt = 0; kt < KC / BCENT; kt++) {   // 8 k-tiles
        const int kb = kt * BCENT;
        float acc[8][8];
#pragma unroll
        for (int i = 0; i < 8; i++)
#pragma unroll
            for (int j = 0; j < 8; j++) acc[i][j] = 0.f;

        for (int dc = 0; dc < D / DCH; dc++) {  // 8 d-chunks
            __syncthreads();   // Bt no longer read by previous chunk
            // stage Bt[dd][c] = C[kb+c][dc*DCH+dd]
            {
                const int dq = t & 3;   // 0..3
                const int c0 = t >> 2;  // 0..63
#pragma unroll
                for (int ic = 0; ic < 2; ic++) {
                    int c = c0 + 64 * ic;
                    const float4 v = *(const float4*)(C + (size_t)(kb + c) * D + dc * DCH + dq * 4);
                    Bt[dq * 4 + 0][c] = v.x;
                    Bt[dq * 4 + 1][c] = v.y;
                    Bt[dq * 4 + 2][c] = v.z;
                    Bt[dq * 4 + 3][c] = v.w;
                }
            }
            __syncthreads();

#pragma unroll
            for (int dd = 0; dd < DCH; dd++) {
                const int d = dc * DCH + dd;
                float4 a0 = *(const float4*)&At[d][ty * 4];
                float4 a1 = *(const float4*)&At[d][64 + ty * 4];
                float4 b0 = *(const float4*)&Bt[dd][tx * 4];
                float4 b1 = *(const float4*)&Bt[dd][64 + tx * 4];
                float av[8] = {a0.x, a0.y, a0.z, a0.w, a1.x, a1.y, a1.z, a1.w};
                float bv[8] = {b0.x, b0.y, b0.z, b0.w, b1.x, b1.y, b1.z, b1.w};
#pragma unroll
                for (int i = 0; i < 8; i++)
#pragma unroll
                    for (int j = 0; j < 8; j++)
                        acc[i][j] = fmaf(av[i], bv[j], acc[i][j]);
            }
        }

        // ---- epilogue for this k-tile: dist2 = CC[k] - 2*dot, argmin ----
        float4 cc0 = *(const float4*)&CC[kb + tx * 4];
        float4 cc1 = *(const float4*)&CC[kb + 64 + tx * 4];
        float ccv[8] = {cc0.x, cc0.y, cc0.z, cc0.w, cc1.x, cc1.y, cc1.z, cc1.w};

#pragma unroll
        for (int i = 0; i < 8; i++) {
            float best = 3.4e38f; int bk = 0x7fffffff;
#pragma unroll
            for (int j = 0; j < 8; j++) {
                int k = kb + ((j < 4) ? (tx * 4 + j) : (64 + tx * 4 + (j - 4)));
                float d2 = fmaf(-2.f, acc[i][j], ccv[j]);
                if (d2 < best || (d2 == best && k < bk)) { best = d2; bk = k; }
            }
            // reduce across the 16 tx lanes (stride-1 within wave)
#pragma unroll
            for (int m = 1; m < 16; m <<= 1) {
                float ob  = __shfl_xor(best, m, 64);
                int   obk = __shfl_xor(bk, m, 64);
                if (ob < best || (ob == best && obk < bk)) { best = ob; bk = obk; }
            }
            if (best < rb[i] || (best == rb[i] && bk < rk[i])) { rb[i] = best; rk[i] = bk; }
        }
    }

    // ---- final: tx==0 lanes hold per-point results ----
    float partial = 0.f;
    if (tx == 0) {
#pragma unroll
        for (int i = 0; i < 8; i++) {
            int pl = (i < 4) ? (ty * 4 + i) : (64 + ty * 4 + (i - 4));
            y_hat[pbase + pl] = rk[i];
            float d2 = xxs[pl] + rb[i];
            partial += sqrtf(fmaxf(d2, 0.f));
        }
    }
#pragma unroll
    for (int m = 1; m < 64; m <<= 1) partial += __shfl_xor(partial, m, 64);
    if ((t & 63) == 0) atomicAdd(inertia, partial);
}

// ---------------- histogram ----------------
__global__ void hist_kernel(const int* __restrict__ y_hat, int* __restrict__ counts) {
    __shared__ int h[KC];
    for (int i = threadIdx.x; i < KC; i += 256) h[i] = 0;
    __syncthreads();
    for (int i = blockIdx.x * 256 + threadIdx.x; i < NPTS; i += gridDim.x * 256)
        atomicAdd(&h[y_hat[i]], 1);
    __syncthreads();
    for (int i = threadIdx.x; i < KC; i += 256) {
        int v = h[i];
        if (v) atomicAdd(&counts[i], v);
    }
}

// ---------------- exclusive scan ----------------
__global__ void scan_kernel(const int* __restrict__ counts, int* __restrict__ cursor) {
    __shared__ int tmp[KC];
    int t = threadIdx.x;
    tmp[t] = counts[t];
    __syncthreads();
    for (int off = 1; off < KC; off <<= 1) {
        int v = tmp[t];
        int add = (t >= off) ? tmp[t - off] : 0;
        __syncthreads();
        tmp[t] = v + add;
        __syncthreads();
    }
    cursor[t] = (t == 0) ? 0 : tmp[t - 1];
}

// ---------------- scatter ----------------
__global__ void scatter_kernel(const int* __restrict__ y_hat,
                               int* __restrict__ cursor,
                               int* __restrict__ order) {
    int i = blockIdx.x * 256 + threadIdx.x;
    if (i < NPTS) {
        int pos = atomicAdd(&cursor[y_hat[i]], 1);
        order[pos] = i;
    }
}

// ---------------- segmented reduction over sorted order ----------------
#define PPB 256
__global__ __launch_bounds__(128) void segsum_kernel(
    const float* __restrict__ X, const float* __restrict__ W,
    const int* __restrict__ order, const int* __restrict__ y_hat,
    float* __restrict__ w_sum, float* __restrict__ xw_sum)
{
    const int d = threadIdx.x;
    const int i0 = blockIdx.x * PPB;
    float wacc = 0.f, xwacc = 0.f;
    int cur = -1;
    for (int i = i0; i < i0 + PPB; i++) {
        int p = order[i];
        int k = y_hat[p];
        if (k != cur) {
            if (cur >= 0) {
                atomicAdd(&w_sum[(size_t)cur * D + d], wacc);
                atomicAdd(&xw_sum[(size_t)cur * D + d], xwacc);
            }
            cur = k; wacc = 0.f; xwacc = 0.f;
        }
        float w = W[(size_t)p * D + d];
        float x = X[(size_t)p * D + d];
        wacc += w;
        xwacc = fmaf(x, w, xwacc);
    }
    if (cur >= 0) {
        atomicAdd(&w_sum[(size_t)cur * D + d], wacc);
        atomicAdd(&xw_sum[(size_t)cur * D + d], xwacc);
    }
}

extern "C" void kernel_launch(void* const* d_in, const int* in_sizes, int n_in,
                              void* d_out, int out_size, void* d_ws, size_t ws_size,
                              hipStream_t stream) {
    const float* X = (const float*)d_in[0];
    const float* W = (const float*)d_in[1];
    const float* C = (const float*)d_in[2];

    float* out     = (float*)d_out;
    float* inertia = out;
    float* w_sum   = out + 1;
    float* xw_sum  = out + 1 + KC * D;

    int*   y_hat  = (int*)d_ws;
    int*   order  = y_hat + NPTS;
    int*   counts = order + NPTS;
    int*   cursor = counts + KC;
    float* CC     = (float*)(cursor + KC);

    hipMemsetAsync(d_out, 0, (size_t)out_size * sizeof(float), stream);
    hipMemsetAsync(counts, 0, KC * sizeof(int), stream);

    cc_kernel<<<(KC + 255) / 256, 256, 0, stream>>>(C, CC);
    assign_kernel<<<NPTS / BPTS, 256, 0, stream>>>(X, C, CC, y_hat, inertia);
    hist_kernel<<<256, 256, 0, stream>>>(y_hat, counts);
    scan_kernel<<<1, KC, 0, stream>>>(counts, cursor);
    scatter_kernel<<<NPTS / 256, 256, 0, stream>>>(y_hat, cursor, order);
    segsum_kernel<<<NPTS / PPB, 128, 0, stream>>>(X, W, order, y_hat, w_sum, xw_sum);
}

// Round 3
// 600.609 us; speedup vs baseline: 4.7481x; 2.3501x over previous
//
#include <hip/hip_runtime.h>
#include <math.h>

#define NPTS 262144
#define D 128
#define KC 1024

typedef __bf16 bf16x8 __attribute__((ext_vector_type(8)));
typedef float floatx4 __attribute__((ext_vector_type(4)));

// ---------------- centroid norms ----------------
__global__ void cc_kernel(const float* __restrict__ C, float* __restrict__ CC) {
    int k = blockIdx.x * 256 + threadIdx.x;
    if (k >= KC) return;
    const float4* Cr = (const float4*)(C + (size_t)k * D);
    float s0 = 0.f, s1 = 0.f, s2 = 0.f, s3 = 0.f;
#pragma unroll
    for (int i = 0; i < D / 4; i++) {
        float4 c = Cr[i];
        s0 = fmaf(c.x, c.x, s0);
        s1 = fmaf(c.y, c.y, s1);
        s2 = fmaf(c.z, c.z, s2);
        s3 = fmaf(c.w, c.w, s3);
    }
    CC[k] = (s0 + s1) + (s2 + s3);
}

// ---------------- assignment: bf16 MFMA GEMM + fused argmin ----------------
// Block: 256 thr = 4 waves. BM=256 pts (wave: 4 m-tiles of 16).
// kt loop: 16 tiles of 64 centroids. mfma_f32_16x16x32_bf16.
// A-frags global->reg once (bf16), exact fp32 ||x||^2 computed en route.
// B staged in LDS in fragment order, XOR-swizzled, double-buffered.
#define BM 256
#define BN 64
#define NKT (KC / BN)   // 16

__global__ __launch_bounds__(256, 2) void assign_kernel(
    const float* __restrict__ X,
    const float* __restrict__ C,
    const float* __restrict__ CC,
    int* __restrict__ y_hat,
    float* __restrict__ inertia)
{
    // Bl[buf][tn][ks][l'][8 bf16] : 2*4*4*64*16B = 32 KB
    __shared__ __align__(16) unsigned short Bl[2][4][4][64][8];
    __shared__ float CCs[KC];   // 4 KB
    __shared__ float xxs[BM];   // 1 KB

    const int t    = threadIdx.x;
    const int w    = t >> 6;
    const int lane = t & 63;
    const int m16  = lane & 15;
    const int quad = lane >> 4;
    const int pbase = blockIdx.x * BM;

    // stage CC -> LDS (coalesced)
    for (int i = t; i < KC; i += 256) CCs[i] = CC[i];

    // ---- load A-fragments (bf16) + exact fp32 ||x||^2 partials ----
    bf16x8 afrag[4][4];
#pragma unroll
    for (int mt = 0; mt < 4; mt++) {
        const int p = pbase + w * 64 + mt * 16 + m16;
        const float* xr = X + (size_t)p * D;
        float xp = 0.f;
#pragma unroll
        for (int ks = 0; ks < 4; ks++) {
            const int d0 = ks * 32 + quad * 8;
            float4 u0 = *(const float4*)(xr + d0);
            float4 u1 = *(const float4*)(xr + d0 + 4);
            xp = fmaf(u0.x, u0.x, xp); xp = fmaf(u0.y, u0.y, xp);
            xp = fmaf(u0.z, u0.z, xp); xp = fmaf(u0.w, u0.w, xp);
            xp = fmaf(u1.x, u1.x, xp); xp = fmaf(u1.y, u1.y, xp);
            xp = fmaf(u1.z, u1.z, xp); xp = fmaf(u1.w, u1.w, xp);
            bf16x8 f;
            f[0] = (__bf16)u0.x; f[1] = (__bf16)u0.y; f[2] = (__bf16)u0.z; f[3] = (__bf16)u0.w;
            f[4] = (__bf16)u1.x; f[5] = (__bf16)u1.y; f[6] = (__bf16)u1.z; f[7] = (__bf16)u1.w;
            afrag[mt][ks] = f;
        }
        // reduce xp over the 4 quads (lanes m16, m16+16, +32, +48)
        xp += __shfl_xor(xp, 16, 64);
        xp += __shfl_xor(xp, 32, 64);
        if (quad == 0) xxs[w * 64 + mt * 16 + m16] = xp;
    }

    float best[4][4];
    int   bk[4][4];
#pragma unroll
    for (int mt = 0; mt < 4; mt++)
#pragma unroll
        for (int r = 0; r < 4; r++) { best[mt][r] = 3.4e38f; bk[mt][r] = 0; }

    // ---- B staging lambda-ish (macro'd inline) ----
    // thread t: cent row c = kb + (t>>2), ks = t&3; 4 groups g of 8 dims.
    const int sc  = t >> 2;        // 0..63
    const int sks = t & 3;
    const int sm  = sc & 15;
    const int stn = t >> 6;

#define STAGE_B(kt_, buf_)                                                        \
    {                                                                             \
        const int kb_ = (kt_) * BN;                                               \
        const float* cr_ = C + (size_t)(kb_ + sc) * D + sks * 32;                 \
        _Pragma("unroll")                                                         \
        for (int g = 0; g < 4; g++) {                                             \
            float4 u0 = *(const float4*)(cr_ + g * 8);                            \
            float4 u1 = *(const float4*)(cr_ + g * 8 + 4);                        \
            bf16x8 f;                                                             \
            f[0] = (__bf16)u0.x; f[1] = (__bf16)u0.y; f[2] = (__bf16)u0.z;        \
            f[3] = (__bf16)u0.w; f[4] = (__bf16)u1.x; f[5] = (__bf16)u1.y;        \
            f[6] = (__bf16)u1.z; f[7] = (__bf16)u1.w;                             \
            const int lp = g * 16 + (sm ^ (sks << 2));                            \
            *(bf16x8*)&Bl[buf_][stn][sks][lp][0] = f;                             \
        }                                                                         \
    }

    STAGE_B(0, 0)
    __syncthreads();

    for (int kt = 0; kt < NKT; kt++) {
        const int cb = kt & 1;
        const int kb = kt * BN;
        if (kt + 1 < NKT) STAGE_B(kt + 1, cb ^ 1)

        // compute this kt
#pragma unroll
        for (int tn = 0; tn < 4; tn++) {
            const int c = kb + tn * 16 + m16;   // this lane's centroid column
            const float ccv = CCs[c];
            floatx4 acc = {0.f, 0.f, 0.f, 0.f};
#pragma unroll
            for (int ks = 0; ks < 4; ks++) {
                const int lp = quad * 16 + (m16 ^ (ks << 2));
                bf16x8 bfr = *(const bf16x8*)&Bl[cb][tn][ks][lp][0];
#pragma unroll
                for (int mt = 0; mt < 4; mt++) {
                    // interleave: accumulate each mt into its own acc? need acc per mt
                    (void)0;
                }
                // NOTE: restructured below — see accs[]
                (void)bfr; (void)acc;
            }
            (void)acc; (void)ccv; (void)c;
            break; // placeholder, real loop below
        }

        // real compute: acc per (mt) inside tn loop
#pragma unroll
        for (int tn = 0; tn < 4; tn++) {
            const int c = kb + tn * 16 + m16;
            const float ccv = CCs[c];
            floatx4 accs[4];
#pragma unroll
            for (int mt = 0; mt < 4; mt++) accs[mt] = (floatx4){0.f, 0.f, 0.f, 0.f};
#pragma unroll
            for (int ks = 0; ks < 4; ks++) {
                const int lp = quad * 16 + (m16 ^ (ks << 2));
                bf16x8 bfr = *(const bf16x8*)&Bl[cb][tn][ks][lp][0];
#pragma unroll
                for (int mt = 0; mt < 4; mt++)
                    accs[mt] = __builtin_amdgcn_mfma_f32_16x16x32_bf16(
                        afrag[mt][ks], bfr, accs[mt], 0, 0, 0);
            }
#pragma unroll
            for (int mt = 0; mt < 4; mt++)
#pragma unroll
                for (int r = 0; r < 4; r++) {
                    float d2 = fmaf(-2.f, accs[mt][r], ccv);
                    if (d2 < best[mt][r]) { best[mt][r] = d2; bk[mt][r] = c; }
                }
        }
        __syncthreads();
    }

    // ---- cross-lane argmin (16 cols per row) ----
#pragma unroll
    for (int mt = 0; mt < 4; mt++)
#pragma unroll
        for (int r = 0; r < 4; r++) {
            float b = best[mt][r]; int k = bk[mt][r];
#pragma unroll
            for (int m = 1; m < 16; m <<= 1) {
                float ob = __shfl_xor(b, m, 64);
                int   ok = __shfl_xor(k, m, 64);
                if (ob < b || (ob == b && ok < k)) { b = ob; k = ok; }
            }
            best[mt][r] = b; bk[mt][r] = k;
        }

    float part = 0.f;
    if (m16 == 0) {
#pragma unroll
        for (int mt = 0; mt < 4; mt++)
#pragma unroll
            for (int r = 0; r < 4; r++) {
                const int row = quad * 4 + r;
                const int p = pbase + w * 64 + mt * 16 + row;
                y_hat[p] = bk[mt][r];
                const float xx = xxs[w * 64 + mt * 16 + row];
                part += sqrtf(fmaxf(xx + best[mt][r], 0.f));
            }
    }
#pragma unroll
    for (int m = 1; m < 64; m <<= 1) part += __shfl_xor(part, m, 64);
    if (lane == 0) atomicAdd(inertia, part);
}

// ---------------- histogram ----------------
__global__ void hist_kernel(const int* __restrict__ y_hat, int* __restrict__ counts) {
    __shared__ int h[KC];
    for (int i = threadIdx.x; i < KC; i += 256) h[i] = 0;
    __syncthreads();
    for (int i = blockIdx.x * 256 + threadIdx.x; i < NPTS; i += gridDim.x * 256)
        atomicAdd(&h[y_hat[i]], 1);
    __syncthreads();
    for (int i = threadIdx.x; i < KC; i += 256) {
        int v = h[i];
        if (v) atomicAdd(&counts[i], v);
    }
}

// ---------------- exclusive scan ----------------
__global__ void scan_kernel(const int* __restrict__ counts, int* __restrict__ cursor) {
    __shared__ int tmp[KC];
    int t = threadIdx.x;
    tmp[t] = counts[t];
    __syncthreads();
    for (int off = 1; off < KC; off <<= 1) {
        int v = tmp[t];
        int add = (t >= off) ? tmp[t - off] : 0;
        __syncthreads();
        tmp[t] = v + add;
        __syncthreads();
    }
    cursor[t] = (t == 0) ? 0 : tmp[t - 1];
}

// ---------------- scatter ----------------
__global__ void scatter_kernel(const int* __restrict__ y_hat,
                               int* __restrict__ cursor,
                               int* __restrict__ order) {
    int i = blockIdx.x * 256 + threadIdx.x;
    if (i < NPTS) {
        int pos = atomicAdd(&cursor[y_hat[i]], 1);
        order[pos] = i;
    }
}

// ---------------- segmented reduction over sorted order ----------------
// LDS-staged (p,k); 2 interleaved halves; depth-2 software prefetch.
#define PPB 256
__global__ __launch_bounds__(256) void segsum_kernel(
    const float* __restrict__ X, const float* __restrict__ W,
    const int* __restrict__ order, const int* __restrict__ y_hat,
    float* __restrict__ w_sum, float* __restrict__ xw_sum)
{
    __shared__ int ps[PPB];
    __shared__ int kk[PPB];
    const int t = threadIdx.x;
    const int i0 = blockIdx.x * PPB;
    {
        int p = order[i0 + t];
        ps[t] = p;
        kk[t] = y_hat[p];
    }
    __syncthreads();

    const int d = t & 127;
    const int g = t >> 7;    // half: points i0+g, i0+g+2, ...

    float wacc = 0.f, xwacc = 0.f;
    int cur = -1;

    int pA = ps[g];
    float xA = X[(size_t)pA * D + d];
    float wA = W[(size_t)pA * D + d];
    int pB = ps[g + 2];
    float xB = X[(size_t)pB * D + d];
    float wB = W[(size_t)pB * D + d];

    for (int i = g; i < PPB; i += 2) {
        float xC = 0.f, wC = 0.f;
        if (i + 4 < PPB) {
            int pC = ps[i + 4];
            xC = X[(size_t)pC * D + d];
            wC = W[(size_t)pC * D + d];
        }
        int k = kk[i];
        if (k != cur) {
            if (cur >= 0) {
                atomicAdd(&w_sum[(size_t)cur * D + d], wacc);
                atomicAdd(&xw_sum[(size_t)cur * D + d], xwacc);
            }
            cur = k; wacc = 0.f; xwacc = 0.f;
        }
        wacc += wA;
        xwacc = fmaf(xA, wA, xwacc);
        xA = xB; wA = wB; xB = xC; wB = wC;
    }
    if (cur >= 0) {
        atomicAdd(&w_sum[(size_t)cur * D + d], wacc);
        atomicAdd(&xw_sum[(size_t)cur * D + d], xwacc);
    }
}

extern "C" void kernel_launch(void* const* d_in, const int* in_sizes, int n_in,
                              void* d_out, int out_size, void* d_ws, size_t ws_size,
                              hipStream_t stream) {
    const float* X = (const float*)d_in[0];
    const float* W = (const float*)d_in[1];
    const float* C = (const float*)d_in[2];

    float* out     = (float*)d_out;
    float* inertia = out;
    float* w_sum   = out + 1;
    float* xw_sum  = out + 1 + KC * D;

    int*   y_hat  = (int*)d_ws;
    int*   order  = y_hat + NPTS;
    int*   counts = order + NPTS;
    int*   cursor = counts + KC;
    float* CC     = (float*)(cursor + KC);

    hipMemsetAsync(d_out, 0, (size_t)out_size * sizeof(float), stream);
    hipMemsetAsync(counts, 0, KC * sizeof(int), stream);

    cc_kernel<<<(KC + 255) / 256, 256, 0, stream>>>(C, CC);
    assign_kernel<<<NPTS / BM, 256, 0, stream>>>(X, C, CC, y_hat, inertia);
    hist_kernel<<<256, 256, 0, stream>>>(y_hat, counts);
    scan_kernel<<<1, KC, 0, stream>>>(counts, cursor);
    scatter_kernel<<<NPTS / 256, 256, 0, stream>>>(y_hat, cursor, order);
    segsum_kernel<<<NPTS / PPB, 256, 0, stream>>>(X, W, order, y_hat, w_sum, xw_sum);
}

// Round 4
// 502.951 us; speedup vs baseline: 5.6700x; 1.1942x over previous
//
#include <hip/hip_runtime.h>
#include <math.h>

#define NPTS 262144
#define D 128
#define KC 1024

typedef __bf16 bf16x8 __attribute__((ext_vector_type(8)));
typedef float floatx4 __attribute__((ext_vector_type(4)));

// ---------------- centroid norms + bf16 convert ----------------
// one block (64 threads) per centroid row: coalesced float2 read,
// ushort2 bf16 write, wave-reduce ||c||^2.
__global__ void cc_kernel(const float* __restrict__ C, float* __restrict__ CC,
                          unsigned short* __restrict__ Cbf) {
    const int row  = blockIdx.x;
    const int lane = threadIdx.x;
    float2 v = *(const float2*)(C + (size_t)row * D + lane * 2);
    __bf16 b0 = (__bf16)v.x, b1 = (__bf16)v.y;
    unsigned short u0, u1;
    __builtin_memcpy(&u0, &b0, 2);
    __builtin_memcpy(&u1, &b1, 2);
    ((ushort2*)Cbf)[(size_t)row * 64 + lane] = make_ushort2(u0, u1);
    float s = fmaf(v.x, v.x, v.y * v.y);
#pragma unroll
    for (int m = 1; m < 64; m <<= 1) s += __shfl_xor(s, m, 64);
    if (lane == 0) CC[row] = s;
}

// ---------------- assignment: barrier-free bf16 MFMA + fused argmin ------
// 256 thr = 4 waves, BM=256 pts/block. Flattened 64-step loop over
// (kt,tn): each step = 16 centroids. B frags loaded straight from
// L1/L2-resident bf16 C (no LDS, no __syncthreads in loop),
// register double-buffered.
#define BM 256

__global__ __launch_bounds__(256, 2) void assign_kernel(
    const float* __restrict__ X,
    const unsigned short* __restrict__ Cbf,
    const float* __restrict__ CC,
    int* __restrict__ y_hat,
    float* __restrict__ inertia)
{
    __shared__ float CCs[KC];   // 4 KB
    __shared__ float xxs[BM];   // 1 KB

    const int t    = threadIdx.x;
    const int w    = t >> 6;
    const int lane = t & 63;
    const int m16  = lane & 15;
    const int quad = lane >> 4;
    const int pbase = blockIdx.x * BM;

    for (int i = t; i < KC; i += 256) CCs[i] = CC[i];

    // ---- A fragments (bf16) + exact fp32 ||x||^2 ----
    bf16x8 afrag[4][4];
#pragma unroll
    for (int mt = 0; mt < 4; mt++) {
        const int p = pbase + w * 64 + mt * 16 + m16;
        const float* xr = X + (size_t)p * D;
        float xp = 0.f;
#pragma unroll
        for (int ks = 0; ks < 4; ks++) {
            const int d0 = ks * 32 + quad * 8;
            float4 u0 = *(const float4*)(xr + d0);
            float4 u1 = *(const float4*)(xr + d0 + 4);
            xp = fmaf(u0.x, u0.x, xp); xp = fmaf(u0.y, u0.y, xp);
            xp = fmaf(u0.z, u0.z, xp); xp = fmaf(u0.w, u0.w, xp);
            xp = fmaf(u1.x, u1.x, xp); xp = fmaf(u1.y, u1.y, xp);
            xp = fmaf(u1.z, u1.z, xp); xp = fmaf(u1.w, u1.w, xp);
            bf16x8 f;
            f[0] = (__bf16)u0.x; f[1] = (__bf16)u0.y; f[2] = (__bf16)u0.z; f[3] = (__bf16)u0.w;
            f[4] = (__bf16)u1.x; f[5] = (__bf16)u1.y; f[6] = (__bf16)u1.z; f[7] = (__bf16)u1.w;
            afrag[mt][ks] = f;
        }
        xp += __shfl_xor(xp, 16, 64);
        xp += __shfl_xor(xp, 32, 64);
        if (quad == 0) xxs[w * 64 + mt * 16 + m16] = xp;
    }
    __syncthreads();   // CCs ready (xxs is same-wave)

    float best[4][4];
    int   bk[4][4];
#pragma unroll
    for (int mt = 0; mt < 4; mt++)
#pragma unroll
        for (int r = 0; r < 4; r++) { best[mt][r] = 3.4e38f; bk[mt][r] = 0; }

    // lane's column base inside a 16-centroid step: row m16, dims quad*8
    const unsigned short* bp = Cbf + (size_t)m16 * D + quad * 8;

    bf16x8 cur[4], nxt[4];
#pragma unroll
    for (int ks = 0; ks < 4; ks++) cur[ks] = *(const bf16x8*)(bp + ks * 32);

    for (int s = 0; s < 64; s++) {
        // prefetch next step's 4 frags (wraps to 0 at the end: harmless)
        const int s1 = (s < 63) ? (s + 1) : 0;
        const unsigned short* np = bp + (size_t)s1 * 16 * D;
#pragma unroll
        for (int ks = 0; ks < 4; ks++) nxt[ks] = *(const bf16x8*)(np + ks * 32);

        floatx4 accs[4];
#pragma unroll
        for (int mt = 0; mt < 4; mt++) accs[mt] = (floatx4){0.f, 0.f, 0.f, 0.f};
#pragma unroll
        for (int ks = 0; ks < 4; ks++)
#pragma unroll
            for (int mt = 0; mt < 4; mt++)
                accs[mt] = __builtin_amdgcn_mfma_f32_16x16x32_bf16(
                    afrag[mt][ks], cur[ks], accs[mt], 0, 0, 0);

        const int c = s * 16 + m16;
        const float ccv = CCs[c];
#pragma unroll
        for (int mt = 0; mt < 4; mt++)
#pragma unroll
            for (int r = 0; r < 4; r++) {
                float d2 = fmaf(-2.f, accs[mt][r], ccv);
                if (d2 < best[mt][r]) { best[mt][r] = d2; bk[mt][r] = c; }
            }
#pragma unroll
        for (int ks = 0; ks < 4; ks++) cur[ks] = nxt[ks];
    }

    // ---- cross-lane argmin over the 16 columns ----
#pragma unroll
    for (int mt = 0; mt < 4; mt++)
#pragma unroll
        for (int r = 0; r < 4; r++) {
            float b = best[mt][r]; int k = bk[mt][r];
#pragma unroll
            for (int m = 1; m < 16; m <<= 1) {
                float ob = __shfl_xor(b, m, 64);
                int   ok = __shfl_xor(k, m, 64);
                if (ob < b || (ob == b && ok < k)) { b = ob; k = ok; }
            }
            best[mt][r] = b; bk[mt][r] = k;
        }

    float part = 0.f;
    if (m16 == 0) {
#pragma unroll
        for (int mt = 0; mt < 4; mt++)
#pragma unroll
            for (int r = 0; r < 4; r++) {
                const int row = quad * 4 + r;
                const int p = pbase + w * 64 + mt * 16 + row;
                y_hat[p] = bk[mt][r];
                const float xx = xxs[w * 64 + mt * 16 + row];
                part += sqrtf(fmaxf(xx + best[mt][r], 0.f));
            }
    }
#pragma unroll
    for (int m = 1; m < 64; m <<= 1) part += __shfl_xor(part, m, 64);
    if (lane == 0) atomicAdd(inertia, part);
}

// ---------------- histogram: 64 blocks, LDS bins, sparse flush ----------
__global__ void hist_kernel(const int* __restrict__ y_hat, int* __restrict__ counts) {
    __shared__ int h[KC];
    for (int i = threadIdx.x; i < KC; i += 256) h[i] = 0;
    __syncthreads();
    for (int i = blockIdx.x * 256 + threadIdx.x; i < NPTS; i += gridDim.x * 256)
        atomicAdd(&h[y_hat[i]], 1);
    __syncthreads();
    for (int i = threadIdx.x; i < KC; i += 256) {
        int v = h[i];
        if (v) atomicAdd(&counts[i], v);
    }
}

// ---------------- exclusive scan ----------------
__global__ void scan_kernel(const int* __restrict__ counts, int* __restrict__ cursor) {
    __shared__ int tmp[KC];
    int t = threadIdx.x;
    tmp[t] = counts[t];
    __syncthreads();
    for (int off = 1; off < KC; off <<= 1) {
        int v = tmp[t];
        int add = (t >= off) ? tmp[t - off] : 0;
        __syncthreads();
        tmp[t] = v + add;
        __syncthreads();
    }
    cursor[t] = (t == 0) ? 0 : tmp[t - 1];
}

// ---------------- scatter: LDS-rank, one cursor bump per (block,bin) -----
#define SPB 2048   // points per scatter block
__global__ __launch_bounds__(256) void scatter_kernel(
    const int* __restrict__ y_hat,
    int* __restrict__ cursor,
    int* __restrict__ order)
{
    __shared__ int h[KC];
    const int t = threadIdx.x;
    const int base_i = blockIdx.x * SPB;
    for (int i = t; i < KC; i += 256) h[i] = 0;
    __syncthreads();
    int myk[SPB / 256], myr[SPB / 256];
#pragma unroll
    for (int j = 0; j < SPB / 256; j++) {
        int k = y_hat[base_i + j * 256 + t];
        myk[j] = k;
        myr[j] = atomicAdd(&h[k], 1);
    }
    __syncthreads();
    for (int b = t; b < KC; b += 256) {
        int c = h[b];
        if (c) h[b] = atomicAdd(&cursor[b], c);   // reuse h[] as base[]
    }
    __syncthreads();
#pragma unroll
    for (int j = 0; j < SPB / 256; j++)
        order[h[myk[j]] + myr[j]] = base_i + j * 256 + t;
}

// ---------------- segmented reduction: depth-4 prefetch ----------------
#define PPB 256
__global__ __launch_bounds__(256) void segsum_kernel(
    const float* __restrict__ X, const float* __restrict__ W,
    const int* __restrict__ order, const int* __restrict__ y_hat,
    float* __restrict__ w_sum, float* __restrict__ xw_sum)
{
    __shared__ int ps[PPB];
    __shared__ int kk[PPB];
    const int t = threadIdx.x;
    const int i0 = blockIdx.x * PPB;
    {
        int p = order[i0 + t];
        ps[t] = p;
        kk[t] = y_hat[p];
    }
    __syncthreads();

    const int d = t & 127;
    const int g = t >> 7;    // half: points g, g+2, ...

    float xs[4], wv[4];
#pragma unroll
    for (int j = 0; j < 4; j++) {
        int p = ps[g + 2 * j];
        xs[j] = X[(size_t)p * D + d];
        wv[j] = W[(size_t)p * D + d];
    }

    float wacc = 0.f, xwacc = 0.f;
    int cur = -1;

#pragma unroll 4
    for (int i = g; i < PPB; i += 2) {
        float xn = 0.f, wn = 0.f;
        if (i + 8 < PPB) {
            int p = ps[i + 8];
            xn = X[(size_t)p * D + d];
            wn = W[(size_t)p * D + d];
        }
        int k = kk[i];
        if (k != cur) {
            if (cur >= 0) {
                atomicAdd(&w_sum[(size_t)cur * D + d], wacc);
                atomicAdd(&xw_sum[(size_t)cur * D + d], xwacc);
            }
            cur = k; wacc = 0.f; xwacc = 0.f;
        }
        wacc += wv[0];
        xwacc = fmaf(xs[0], wv[0], xwacc);
        xs[0] = xs[1]; xs[1] = xs[2]; xs[2] = xs[3]; xs[3] = xn;
        wv[0] = wv[1]; wv[1] = wv[2]; wv[2] = wv[3]; wv[3] = wn;
    }
    if (cur >= 0) {
        atomicAdd(&w_sum[(size_t)cur * D + d], wacc);
        atomicAdd(&xw_sum[(size_t)cur * D + d], xwacc);
    }
}

extern "C" void kernel_launch(void* const* d_in, const int* in_sizes, int n_in,
                              void* d_out, int out_size, void* d_ws, size_t ws_size,
                              hipStream_t stream) {
    const float* X = (const float*)d_in[0];
    const float* W = (const float*)d_in[1];
    const float* C = (const float*)d_in[2];

    float* out     = (float*)d_out;
    float* inertia = out;
    float* w_sum   = out + 1;
    float* xw_sum  = out + 1 + KC * D;

    int*   y_hat  = (int*)d_ws;
    int*   order  = y_hat + NPTS;
    int*   counts = order + NPTS;
    int*   cursor = counts + KC;
    float* CC     = (float*)(cursor + KC);
    unsigned short* Cbf = (unsigned short*)(CC + KC);   // 1024*128 bf16, 16B-aligned

    hipMemsetAsync(d_out, 0, (size_t)out_size * sizeof(float), stream);
    hipMemsetAsync(counts, 0, KC * sizeof(int), stream);

    cc_kernel<<<KC, 64, 0, stream>>>(C, CC, Cbf);
    assign_kernel<<<NPTS / BM, 256, 0, stream>>>(X, Cbf, CC, y_hat, inertia);
    hist_kernel<<<64, 256, 0, stream>>>(y_hat, counts);
    scan_kernel<<<1, KC, 0, stream>>>(counts, cursor);
    scatter_kernel<<<NPTS / SPB, 256, 0, stream>>>(y_hat, cursor, order);
    segsum_kernel<<<NPTS / PPB, 256, 0, stream>>>(X, W, order, y_hat, w_sum, xw_sum);
}